// Round 2
// baseline (142.267 us; speedup 1.0000x reference)
//
#include <hip/hip_runtime.h>

// Problem constants (fixed by reference setup_inputs)
constexpr int Bc   = 4;
constexpr int Cc   = 3;
constexpr int Hc   = 160;
constexpr int Wc   = 160;
constexpr int Hoc  = 158;
constexpr int Woc  = 158;
constexpr int Lc   = Hoc * Woc;    // 24964
constexpr int Ntot = Bc * Lc;      // 99856
constexpr int NCH  = 8;
constexpr int MDd  = 54;           // 2 * C * 3 * 3

// Bijective (involutive) map float-bits <-> uint such that ascending uint
// == DESCENDING float. kd = sign ? u : (~u & 0x7FFFFFFF). Applying the same
// formula to kd recovers u exactly.
__device__ __forceinline__ unsigned inv_key_bits(unsigned u) {
    return (u & 0x80000000u) ? u : (~u & 0x7FFFFFFFu);
}
__device__ __forceinline__ unsigned inv_key(float f) {
    return inv_key_bits(__float_as_uint(f));
}

__global__ __launch_bounds__(256) void wos_kernel(
    const float* __restrict__ x, const float* __restrict__ weight,
    const float* __restrict__ bias, const float* __restrict__ mask,
    float* __restrict__ out)
{
    __shared__ float s_w[NCH * MDd];   // weights, 1728 B
    __shared__ float s_m[NCH * MDd];   // masks,   1728 B
    for (int t = threadIdx.x; t < NCH * MDd; t += 256) {
        s_w[t] = weight[t];
        s_m[t] = mask[t];
    }
    __syncthreads();

    const int lane = threadIdx.x & 63;
    const int wave = threadIdx.x >> 6;           // wave-uniform nc
    const int grp  = blockIdx.x >> 1;
    const int nc   = ((blockIdx.x & 1) << 2) | wave;
    const int n    = grp * 64 + lane;
    if (n >= Ntot) return;

    const int b  = n / Lc;
    const int l  = n - b * Lc;
    const int ho = l / Woc;
    const int wo = l - ho * Woc;

    const float* xb = x + (b * Cc) * (Hc * Wc);
    const float* mk = s_m + nc * MDd;            // wave-uniform LDS broadcast
    const float* wr = s_w + nc * MDd;
    const float  bi = bias[nc];

    // 64-bit sortable items: high word = exact 32-bit descending-order key of
    // mx (bit-faithful fp32 comparator), low word = this element's weight
    // bits (payload; also the tie-break — exact fp32 ties are measure-zero).
    unsigned long long it[64];
    #pragma unroll
    for (int c = 0; c < 3; ++c) {
        #pragma unroll
        for (int r = 0; r < 3; ++r) {
            #pragma unroll
            for (int s = 0; s < 3; ++s) {
                const int d = c * 9 + r * 3 + s;
                const float v = xb[(c * Hc + ho + r) * Wc + wo + s];
                const float m0 =  v + mk[d];
                const float m1 = -v + mk[27 + d];
                it[d] = ((unsigned long long)inv_key(m0) << 32)
                        | __float_as_uint(wr[d]);
                it[27 + d] = ((unsigned long long)inv_key(m1) << 32)
                             | __float_as_uint(wr[27 + d]);
            }
        }
    }
    #pragma unroll
    for (int d = MDd; d < 64; ++d) it[d] = 0xFFFFFFFFFFFFFFFFull; // pad: last

    // Fully-unrolled 64-element bitonic sort (ascending u64 == descending mx).
    #pragma unroll
    for (int kk = 2; kk <= 64; kk <<= 1) {
        #pragma unroll
        for (int jj = kk >> 1; jj > 0; jj >>= 1) {
            #pragma unroll
            for (int i = 0; i < 64; ++i) {
                const int p = i ^ jj;
                if (p > i) {
                    const unsigned long long a = it[i], c2 = it[p];
                    const bool sw = a < c2;
                    const unsigned long long lo = sw ? a : c2;
                    const unsigned long long hi = sw ? c2 : a;
                    if ((i & kk) == 0) { it[i] = lo; it[p] = hi; }
                    else               { it[i] = hi; it[p] = lo; }
                }
            }
        }
    }

    // Sequential fp32 cumsum of weights in sorted (descending-mx) order —
    // bit-matches the reference. Track the key of the last rank whose
    // cumulative weight <= bias; default (clip-to-0) is rank 0's key.
    float acc = 0.0f;
    unsigned sel = (unsigned)(it[0] >> 32);
    #pragma unroll
    for (int r = 0; r < MDd; ++r) {
        const unsigned wbits = (unsigned)it[r];
        const unsigned kbits = (unsigned)(it[r] >> 32);
        acc += __uint_as_float(wbits);
        sel = (acc <= bi) ? kbits : sel;
    }

    // Invert the (involutive) key transform to recover the exact fp32 value.
    out[n * NCH + nc] = __uint_as_float(inv_key_bits(sel));
}

extern "C" void kernel_launch(void* const* d_in, const int* in_sizes, int n_in,
                              void* d_out, int out_size, void* d_ws, size_t ws_size,
                              hipStream_t stream) {
    const float* x      = (const float*)d_in[0];
    const float* weight = (const float*)d_in[1];
    const float* bias   = (const float*)d_in[2];
    const float* mask   = (const float*)d_in[3];
    float* out = (float*)d_out;

    const int ngrp = (Ntot + 63) / 64;      // 1561
    dim3 grid(ngrp * 2);                    // ×2 blocks: 8 nc / 4 waves
    wos_kernel<<<grid, 256, 0, stream>>>(x, weight, bias, mask, out);
}

// Round 3
// 132.370 us; speedup vs baseline: 1.0748x; 1.0748x over previous
//
#include <hip/hip_runtime.h>

// Problem constants (fixed by reference setup_inputs)
constexpr int Cc   = 3;
constexpr int Hc   = 160;
constexpr int Wc   = 160;
constexpr int Hoc  = 158;
constexpr int Woc  = 158;
constexpr int Lc   = Hoc * Woc;    // 24964
constexpr int Ntot = 4 * Lc;       // 99856
constexpr int NCH  = 8;
constexpr int MDd  = 54;           // 2 * C * 3 * 3

// Bijective (involutive) map float-bits <-> uint such that ascending uint
// == DESCENDING float. Applying it twice recovers the original bits.
__device__ __forceinline__ unsigned inv_key_bits(unsigned u) {
    return (u & 0x80000000u) ? u : (~u & 0x7FFFFFFFu);
}
__device__ __forceinline__ unsigned inv_key(float f) {
    return inv_key_bits(__float_as_uint(f));
}

// launch_bounds(256,2): 2 waves/EU -> 256 unified regs/wave, so the 54 live
// u64 items (~108 regs) + temps stay in arch VGPRs (no AGPR ping-pong tax).
__global__ __launch_bounds__(256, 2) void wos_kernel(
    const float* __restrict__ x, const float* __restrict__ weight,
    const float* __restrict__ bias, const float* __restrict__ mask,
    float* __restrict__ out)
{
    const int lane = threadIdx.x & 63;
    const int wave = threadIdx.x >> 6;
    const int grp  = blockIdx.x >> 1;
    // nc is wave-uniform: assert it so weight/mask/bias reads become scalar loads.
    const int nc   = __builtin_amdgcn_readfirstlane(((blockIdx.x & 1) << 2) | wave);
    const int n    = grp * 64 + lane;
    if (n >= Ntot) return;

    const int b  = n / Lc;
    const int l  = n - b * Lc;
    const int ho = l / Woc;
    const int wo = l - ho * Woc;

    const float* xb = x + (b * Cc) * (Hc * Wc);
    const float* mk = mask + nc * MDd;      // wave-uniform -> SMEM
    const float* wr = weight + nc * MDd;    // wave-uniform -> SMEM
    const float  bi = bias[nc];

    // 64-bit sortable items: high word = exact 32-bit descending-order key of
    // mx (bit-faithful fp32 comparator), low word = element's weight bits
    // (payload; also tie-break — exact fp32 ties are measure-zero).
    unsigned long long it[MDd];
    #pragma unroll
    for (int c = 0; c < 3; ++c) {
        #pragma unroll
        for (int r = 0; r < 3; ++r) {
            #pragma unroll
            for (int s = 0; s < 3; ++s) {
                const int d = c * 9 + r * 3 + s;
                const float v = xb[(c * Hc + ho + r) * Wc + wo + s];
                const float m0 =  v + mk[d];
                const float m1 = -v + mk[27 + d];
                it[d] = ((unsigned long long)inv_key(m0) << 32)
                        | __float_as_uint(wr[d]);
                it[27 + d] = ((unsigned long long)inv_key(m1) << 32)
                             | __float_as_uint(wr[27 + d]);
            }
        }
    }

    // Batcher odd-even mergesort for n=64, pruned to wires < 54.
    // Monotone (all CEs ascending) => virtual +inf pads on wires 54..63 never
    // move down, so every CE with hi >= 54 is a static no-op; the pruned
    // network is a valid 54-input sorting network (~420 CEs vs 672 bitonic).
    #pragma unroll
    for (int p = 1; p < 64; p <<= 1) {
        #pragma unroll
        for (int k = p; k >= 1; k >>= 1) {
            #pragma unroll
            for (int j = k % p; j + k < 64; j += 2 * k) {
                #pragma unroll
                for (int i = 0; i < k; ++i) {
                    const int lo = i + j;
                    const int hi = i + j + k;
                    if (hi < MDd && (lo / (2 * p) == hi / (2 * p))) {
                        const unsigned long long a = it[lo], c2 = it[hi];
                        const bool sw = a < c2;
                        it[lo] = sw ? a : c2;
                        it[hi] = sw ? c2 : a;
                    }
                }
            }
        }
    }

    // Sequential fp32 cumsum of weights in sorted (descending-mx) order —
    // bit-matches the reference. Track the key of the last rank whose
    // cumulative weight <= bias; default (clip-to-0) is rank 0's key.
    float acc = 0.0f;
    unsigned sel = (unsigned)(it[0] >> 32);
    #pragma unroll
    for (int r = 0; r < MDd; ++r) {
        acc += __uint_as_float((unsigned)it[r]);
        sel = (acc <= bi) ? (unsigned)(it[r] >> 32) : sel;
    }

    // Invert the (involutive) key transform to recover the exact fp32 value.
    out[n * NCH + nc] = __uint_as_float(inv_key_bits(sel));
}

extern "C" void kernel_launch(void* const* d_in, const int* in_sizes, int n_in,
                              void* d_out, int out_size, void* d_ws, size_t ws_size,
                              hipStream_t stream) {
    const float* x      = (const float*)d_in[0];
    const float* weight = (const float*)d_in[1];
    const float* bias   = (const float*)d_in[2];
    const float* mask   = (const float*)d_in[3];
    float* out = (float*)d_out;

    const int ngrp = (Ntot + 63) / 64;      // 1561
    dim3 grid(ngrp * 2);                    // x2 blocks: 8 nc / 4 waves
    wos_kernel<<<grid, 256, 0, stream>>>(x, weight, bias, mask, out);
}

// Round 4
// 129.123 us; speedup vs baseline: 1.1018x; 1.0251x over previous
//
#include <hip/hip_runtime.h>

// Problem constants (fixed by reference setup_inputs)
constexpr int Cc   = 3;
constexpr int Hc   = 160;
constexpr int Wc   = 160;
constexpr int Hoc  = 158;
constexpr int Woc  = 158;
constexpr int Lc   = Hoc * Woc;    // 24964
constexpr int Ntot = 4 * Lc;       // 99856
constexpr int NCH  = 8;
constexpr int MDd  = 54;           // 2 * C * 3 * 3

// Bijective (involutive) map float-bits <-> uint such that ascending uint
// == DESCENDING float. Applying it twice recovers the original bits.
__device__ __forceinline__ unsigned inv_key_bits(unsigned u) {
    return (u & 0x80000000u) ? u : (~u & 0x7FFFFFFFu);
}
__device__ __forceinline__ unsigned inv_key(float f) {
    return inv_key_bits(__float_as_uint(f));
}

// Compare-exchange on (key, pay) pairs, ascending lexicographic (key, pay) —
// bit-identical to a u64 compare of (key<<32 | pay) (round-3 semantics).
// Inline asm with "v" constraints pins every sort value in ARCH VGPRS (the
// compiler was parking the array in AGPRs and paying accvgpr shuttles around
// every CE — the measured 2.3x VALU-instruction inflation).
// vcc = borrow of (ka,pa)-(kb,pb) = (ka<kb) || (ka==kb && pa<pb).
__device__ __forceinline__ void ce(unsigned &ka, unsigned &pa,
                                   unsigned &kb, unsigned &pb) {
    unsigned nka, nkb, npa, npb, t;
    asm("v_sub_co_u32 %4, vcc, %6, %8\n\t"
        "v_subb_co_u32 %4, vcc, %5, %7, vcc\n\t"
        "v_cndmask_b32 %0, %7, %5, vcc\n\t"
        "v_cndmask_b32 %1, %5, %7, vcc\n\t"
        "v_cndmask_b32 %2, %8, %6, vcc\n\t"
        "v_cndmask_b32 %3, %6, %8, vcc"
        : "=&v"(nka), "=&v"(nkb), "=&v"(npa), "=&v"(npb), "=&v"(t)
        : "v"(ka), "v"(pa), "v"(kb), "v"(pb)
        : "vcc");
    ka = nka; kb = nkb; pa = npa; pb = npb;
}

__global__ __launch_bounds__(256) void wos_kernel(
    const float* __restrict__ x, const float* __restrict__ weight,
    const float* __restrict__ bias, const float* __restrict__ mask,
    float* __restrict__ out)
{
    const int lane = threadIdx.x & 63;
    const int wave = threadIdx.x >> 6;
    const int grp  = blockIdx.x >> 1;
    // nc is wave-uniform: assert it so weight/mask/bias reads become scalar loads.
    const int nc   = __builtin_amdgcn_readfirstlane(((blockIdx.x & 1) << 2) | wave);
    const int n    = grp * 64 + lane;
    if (n >= Ntot) return;

    const int b  = n / Lc;
    const int l  = n - b * Lc;
    const int ho = l / Woc;
    const int wo = l - ho * Woc;

    const float* xb = x + (b * Cc) * (Hc * Wc);
    const float* mk = mask + nc * MDd;      // wave-uniform -> scalar loads
    const float* wr = weight + nc * MDd;    // wave-uniform -> scalar loads
    const float  bi = bias[nc];

    // key = exact 32-bit descending-order comparator of mx; pay = weight bits
    // (payload + tie-break; ascending-u32 on weights in (0,1) == ascending float).
    unsigned key[MDd], pay[MDd];
    #pragma unroll
    for (int c = 0; c < 3; ++c) {
        #pragma unroll
        for (int r = 0; r < 3; ++r) {
            #pragma unroll
            for (int s = 0; s < 3; ++s) {
                const int d = c * 9 + r * 3 + s;
                const float v = xb[(c * Hc + ho + r) * Wc + wo + s];
                key[d]      = inv_key( v + mk[d]);
                key[27 + d] = inv_key(-v + mk[27 + d]);
                pay[d]      = __float_as_uint(wr[d]);
                pay[27 + d] = __float_as_uint(wr[27 + d]);
            }
        }
    }

    // Batcher odd-even mergesort for n=64, pruned to wires < 54 (monotone
    // network => +inf pads on wires 54..63 are static no-ops). Same network
    // as round 3 (correctness-proven); only the CE body changed.
    #pragma unroll
    for (int p = 1; p < 64; p <<= 1) {
        #pragma unroll
        for (int k = p; k >= 1; k >>= 1) {
            #pragma unroll
            for (int j = k % p; j + k < 64; j += 2 * k) {
                #pragma unroll
                for (int i = 0; i < k; ++i) {
                    const int lo = i + j;
                    const int hi = i + j + k;
                    if (hi < MDd && (lo / (2 * p) == hi / (2 * p))) {
                        ce(key[lo], pay[lo], key[hi], pay[hi]);
                    }
                }
            }
        }
    }

    // Sequential fp32 cumsum of weights in sorted (descending-mx) order —
    // bit-matches the reference. Track the key of the last rank whose
    // cumulative weight <= bias; default (clip-to-0) is rank 0's key.
    float acc = 0.0f;
    unsigned sel = key[0];
    #pragma unroll
    for (int r = 0; r < MDd; ++r) {
        acc += __uint_as_float(pay[r]);
        sel = (acc <= bi) ? key[r] : sel;
    }

    // Invert the (involutive) key transform to recover the exact fp32 value.
    out[n * NCH + nc] = __uint_as_float(inv_key_bits(sel));
}

extern "C" void kernel_launch(void* const* d_in, const int* in_sizes, int n_in,
                              void* d_out, int out_size, void* d_ws, size_t ws_size,
                              hipStream_t stream) {
    const float* x      = (const float*)d_in[0];
    const float* weight = (const float*)d_in[1];
    const float* bias   = (const float*)d_in[2];
    const float* mask   = (const float*)d_in[3];
    float* out = (float*)d_out;

    const int ngrp = (Ntot + 63) / 64;      // 1561
    dim3 grid(ngrp * 2);                    // x2 blocks: 8 nc / 4 waves
    wos_kernel<<<grid, 256, 0, stream>>>(x, weight, bias, mask, out);
}